// Round 3
// baseline (222.690 us; speedup 1.0000x reference)
//
#include <hip/hip_runtime.h>
#include <hip/hip_bf16.h>

#define BB   16
#define DD   256
#define HH   8
#define HDIM 32
#define WW   512
#define NC   511   // rows in k_cache / v_cache

// dot of a 256-elem fp32 row with a 256-elem fp32 LDS vector
__device__ __forceinline__ float dot256f(const float* __restrict__ row,
                                         const float* __restrict__ v) {
    const float4* r4 = (const float4*)row;
    float acc = 0.f;
    #pragma unroll 8
    for (int i = 0; i < 64; ++i) {
        float4 w = r4[i];
        acc += w.x * v[4 * i] + w.y * v[4 * i + 1] + w.z * v[4 * i + 2] + w.w * v[4 * i + 3];
    }
    return acc;
}

__global__ __launch_bounds__(256) void fused_decode(
    const float* __restrict__ emb,      // VOCAB*256 f32
    const int*   __restrict__ tokens,   // 16
    const float* __restrict__ pos_emb,  // 512*256
    const float* __restrict__ rms_w,    // 256
    const float* __restrict__ wq,       // 256*256
    const float* __restrict__ bq,       // 256
    const float* __restrict__ wk,       // 32*256
    const float* __restrict__ bk,       // 32
    const float* __restrict__ wv,       // 256*256
    const float* __restrict__ bv,       // 256
    const float* __restrict__ kc,       // 16*511*32
    const float* __restrict__ vc,       // 16*511*256
    const float* __restrict__ cosd,     // 512*32 (already repeat-2)
    const float* __restrict__ sind,     // 512*32
    const float* __restrict__ maskd,    // 512*512, row 0 used
    float*       __restrict__ out)      // 16*256 f32
{
    const int tid = threadIdx.x;
    const int b = blockIdx.x >> 3;   // / HH
    const int h = blockIdx.x & 7;    // % HH

    __shared__ float xs[DD];
    __shared__ float hs[DD];
    __shared__ float qraw[HDIM];
    __shared__ float qr[HDIM];
    __shared__ float knew[HDIM];
    __shared__ float vnew[DD];
    __shared__ float probs[WW];
    __shared__ float red[4];
    __shared__ float pv[8][HDIM];

    // ---- 1. x = emb[token] + pos_emb[W-1]; RMSNorm ----
    const int tok = tokens[b];
    const float x = emb[(size_t)tok * DD + tid] + pos_emb[(size_t)(WW - 1) * DD + tid];
    xs[tid] = x;
    float ss = x * x;
    #pragma unroll
    for (int off = 32; off > 0; off >>= 1) ss += __shfl_down(ss, off, 64);
    if ((tid & 63) == 0) red[tid >> 6] = ss;
    __syncthreads();
    const float mean = (red[0] + red[1] + red[2] + red[3]) * (1.0f / DD);
    const float rinv = rsqrtf(mean + 1.1920928955078125e-07f);
    hs[tid] = x * rinv * rms_w[tid];
    __syncthreads();

    // ---- 2. gemvs: q head h (32 outs), k_new (32 outs), v_new (head 7 only) ----
    if (tid < HDIM) {
        qraw[tid] = dot256f(wq + (size_t)(h * HDIM + tid) * DD, hs) + bq[h * HDIM + tid];
    } else if (tid < 2 * HDIM) {
        const int o = tid - HDIM;
        knew[o] = dot256f(wk + (size_t)o * DD, hs) + bk[o];
    }
    if (h == 7) {
        vnew[tid] = dot256f(wv + (size_t)tid * DD, hs) + bv[tid];
    }
    __syncthreads();

    // ---- 3. rope q with table row 1; fold in 1/sqrt(HD) ----
    if (tid < HDIM) {
        const float c = cosd[1 * HDIM + tid];
        const float s = sind[1 * HDIM + tid];
        const float te = qraw[tid & ~1], to = qraw[tid | 1];
        const float v = (tid & 1) ? (te * s + to * c) : (te * c - to * s);
        qr[tid] = v * 0.17677669529663687f;   // 1/sqrt(32)
    }
    __syncthreads();

    // ---- 4. scores: each thread handles w = tid and w = tid + 256 ----
    float sv[2];
    float smax = -INFINITY;
    #pragma unroll
    for (int r = 0; r < 2; ++r) {
        const int w = tid + r * 256;
        float kv[HDIM];
        if (w < NC) {
            const float4* krow = (const float4*)(kc + ((size_t)b * NC + w) * HDIM);
            #pragma unroll
            for (int i = 0; i < 8; ++i) {
                float4 t = krow[i];
                kv[4 * i] = t.x; kv[4 * i + 1] = t.y; kv[4 * i + 2] = t.z; kv[4 * i + 3] = t.w;
            }
        } else {
            #pragma unroll
            for (int i = 0; i < HDIM; ++i) kv[i] = knew[i];
        }
        float acc = 0.f;
        #pragma unroll
        for (int i = 0; i < HDIM; i += 2) {
            const float c = cosd[w * HDIM + i];
            const float s = sind[w * HDIM + i];
            const float k0 = kv[i] * c - kv[i + 1] * s;
            const float k1 = kv[i] * s + kv[i + 1] * c;
            acc += qr[i] * k0 + qr[i + 1] * k1;
        }
        if (maskd[w] == 0.0f) acc = -INFINITY;
        sv[r] = acc;
        smax = fmaxf(smax, acc);
    }

    // ---- 5. softmax over 512 ----
    #pragma unroll
    for (int off = 32; off > 0; off >>= 1) smax = fmaxf(smax, __shfl_down(smax, off, 64));
    __syncthreads();                    // red free for reuse
    if ((tid & 63) == 0) red[tid >> 6] = smax;
    __syncthreads();
    const float gmax = fmaxf(fmaxf(red[0], red[1]), fmaxf(red[2], red[3]));
    float esum = 0.f;
    #pragma unroll
    for (int r = 0; r < 2; ++r) {
        const float e = expf(sv[r] - gmax);
        probs[tid + r * 256] = e;       // unnormalized; scale at end
        esum += e;
    }
    #pragma unroll
    for (int off = 32; off > 0; off >>= 1) esum += __shfl_down(esum, off, 64);
    __syncthreads();                    // gmax reads done
    if ((tid & 63) == 0) red[tid >> 6] = esum;
    __syncthreads();
    const float inv = 1.0f / (red[0] + red[1] + red[2] + red[3]);

    // ---- 6. PV with the raw-reshape mapping:
    // v_all[b,h,w,hd] = v_orig[b, h*64 + w/8, (w%8)*32 + hd]; row 511 = v_new
    const int hd = tid & 31;
    const int seg = tid >> 5;           // 0..7, each covers 64 w's
    float acc = 0.f;
    const int wbase = seg * 64;
    for (int j = 0; j < 64; ++j) {
        const int w = wbase + j;
        const int row = h * 64 + (w >> 3);
        const int col = ((w & 7) << 5) + hd;
        const float v = (row < NC) ? vc[((size_t)b * NC + row) * DD + col]
                                   : vnew[col];
        acc += probs[w] * v;
    }
    pv[seg][hd] = acc;
    __syncthreads();

    // ---- 7. reduce segments, residual, store ----
    if (tid < HDIM) {
        float o = 0.f;
        #pragma unroll
        for (int s2 = 0; s2 < 8; ++s2) o += pv[s2][tid];
        o = o * inv + xs[h * HDIM + tid];
        out[(size_t)b * DD + h * HDIM + tid] = o;
    }
}

extern "C" void kernel_launch(void* const* d_in, const int* in_sizes, int n_in,
                              void* d_out, int out_size, void* d_ws, size_t ws_size,
                              hipStream_t stream) {
    const float* emb     = (const float*)d_in[0];
    const int*   tokens  = (const int*)d_in[1];
    const float* pos_emb = (const float*)d_in[2];
    const float* rms_w   = (const float*)d_in[3];
    const float* wq      = (const float*)d_in[4];
    const float* bq      = (const float*)d_in[5];
    const float* wk      = (const float*)d_in[6];
    const float* bk      = (const float*)d_in[7];
    const float* wv      = (const float*)d_in[8];
    const float* bv      = (const float*)d_in[9];
    const float* kc      = (const float*)d_in[10];
    const float* vc      = (const float*)d_in[11];
    const float* cosd    = (const float*)d_in[12];
    const float* sind    = (const float*)d_in[13];
    const float* maskd   = (const float*)d_in[14];
    float* out           = (float*)d_out;

    fused_decode<<<dim3(BB * HH), dim3(256), 0, stream>>>(
        emb, tokens, pos_emb, rms_w, wq, bq, wk, bk, wv, bv,
        kc, vc, cosd, sind, maskd, out);
}

// Round 4
// 204.902 us; speedup vs baseline: 1.0868x; 1.0868x over previous
//
#include <hip/hip_runtime.h>
#include <hip/hip_bf16.h>

#define BB   16
#define DD   256
#define HH   8
#define HDIM 32
#define WW   512
#define NC   511   // rows in k_cache / v_cache
#define EPS  1.1920928955078125e-07f

// async global->LDS, 16B per lane: lds dest = uniform base + lane*16
__device__ __forceinline__ void g2l16(const float* g, float* l) {
    __builtin_amdgcn_global_load_lds(
        (const __attribute__((address_space(1))) unsigned int*)g,
        (__attribute__((address_space(3))) unsigned int*)l, 16, 0, 0);
}

__global__ __launch_bounds__(256, 1) void fused_decode(
    const float* __restrict__ emb,      // VOCAB*256 f32
    const int*   __restrict__ tokens,   // 16
    const float* __restrict__ pos_emb,  // 512*256
    const float* __restrict__ rms_w,    // 256
    const float* __restrict__ wq,       // 256*256
    const float* __restrict__ bq,       // 256
    const float* __restrict__ wk,       // 32*256
    const float* __restrict__ bk,       // 32
    const float* __restrict__ wv,       // 256*256
    const float* __restrict__ bv,       // 256
    const float* __restrict__ kc,       // 16*511*32
    const float* __restrict__ vc,       // 16*511*256
    const float* __restrict__ cosd,     // 512*32 (repeat-2 layout)
    const float* __restrict__ sind,     // 512*32
    const float* __restrict__ maskd,    // 512*512, row 0 used
    float*       __restrict__ out)      // 16*256 f32
{
    const int tid  = threadIdx.x;
    const int lane = tid & 63;
    const int wid  = tid >> 6;
    const int b = blockIdx.x >> 3;   // / HH
    const int h = blockIdx.x & 7;    // % HH

    __shared__ __align__(16) float vs[64][DD];   // 64 KB: this block's V slice
    __shared__ __align__(16) float xs[DD];
    __shared__ __align__(16) float hs[DD];
    __shared__ float qraw[HDIM];
    __shared__ float qr[HDIM];
    __shared__ float knew[HDIM];
    __shared__ float probs[WW];
    __shared__ float red[4];
    __shared__ float pv[8][HDIM];

    // ============ phase 0: issue ALL independent global loads ============
    // v_all[b,h,w,hd] = v_orig[b, h*64 + w/8, (w%8)*32 + hd]; local row r=w>>3.
    // Prefetch the 64 vc rows this head needs straight into LDS.
    {
        const int rbase = wid * 16;
        #pragma unroll
        for (int rr = 0; rr < 16; ++rr) {
            const int r = rbase + rr;
            if (h == 7 && r == 63) continue;   // global row 511 = v_new (patched later)
            g2l16(vc + ((size_t)(b * NC + h * 64 + r)) * DD + lane * 4, &vs[r][0]);
        }
    }
    // K rows for w=tid and w=tid+256, plus their cos/sin rows, into registers.
    float4 kA[8], kB[8], cA[8], sA[8], cB[8], sB[8];
    {
        const float4* p = (const float4*)(kc + ((size_t)b * NC + tid) * HDIM);
        #pragma unroll
        for (int i = 0; i < 8; ++i) kA[i] = p[i];
    }
    const int w2 = tid + 256;
    if (w2 < NC) {
        const float4* p = (const float4*)(kc + ((size_t)b * NC + w2) * HDIM);
        #pragma unroll
        for (int i = 0; i < 8; ++i) kB[i] = p[i];
    } else {
        #pragma unroll
        for (int i = 0; i < 8; ++i) kB[i] = make_float4(0.f, 0.f, 0.f, 0.f);
    }
    {
        const float4* pc = (const float4*)(cosd + (size_t)tid * HDIM);
        const float4* ps = (const float4*)(sind + (size_t)tid * HDIM);
        const float4* qc = (const float4*)(cosd + (size_t)w2 * HDIM);
        const float4* qs = (const float4*)(sind + (size_t)w2 * HDIM);
        #pragma unroll
        for (int i = 0; i < 8; ++i) { cA[i] = pc[i]; sA[i] = ps[i]; cB[i] = qc[i]; sB[i] = qs[i]; }
    }
    const int tok = tokens[b];
    const float xv = emb[(size_t)tok * DD + tid] + pos_emb[(size_t)(WW - 1) * DD + tid];
    const float rw  = rms_w[tid];
    const float mA  = maskd[tid];
    const float mB  = maskd[tid + 256];
    const int   o   = tid >> 2, p4 = tid & 3;      // gemv: 4 threads per output
    const float bias = (o < HDIM) ? bq[h * HDIM + o] : bk[o - HDIM];
    const float bvv  = (h == 7) ? bv[tid] : 0.f;
    const float cq = cosd[HDIM + (tid & 31)];       // rope row 1 for q
    const float sq = sind[HDIM + (tid & 31)];

    // ============ RMSNorm ============
    xs[tid] = xv;
    float ssum = xv * xv;
    #pragma unroll
    for (int off = 32; off > 0; off >>= 1) ssum += __shfl_down(ssum, off, 64);
    if (lane == 0) red[wid] = ssum;
    __syncthreads();                                 // B1: drains ALL prefetches
    const float mean = (red[0] + red[1] + red[2] + red[3]) * (1.0f / DD);
    const float rinv = rsqrtf(mean + EPS);
    hs[tid] = xv * rinv * rw;
    __syncthreads();                                 // B2

    // ============ gemvs: q head (o<32) / k_new (o>=32), 4 threads per out ====
    {
        const float* row = (o < HDIM) ? (wq + (size_t)(h * HDIM + o) * DD)
                                      : (wk + (size_t)(o - HDIM) * DD);
        const float4* r4 = (const float4*)(row + p4 * 64);
        const float4* h4 = (const float4*)(hs + p4 * 64);
        float acc = 0.f;
        #pragma unroll
        for (int i = 0; i < 16; ++i) {
            const float4 wv4 = r4[i], hh = h4[i];
            acc += wv4.x * hh.x + wv4.y * hh.y + wv4.z * hh.z + wv4.w * hh.w;
        }
        acc += __shfl_xor(acc, 1, 64);
        acc += __shfl_xor(acc, 2, 64);
        if (p4 == 0) {
            acc += bias;
            if (o < HDIM) qraw[o] = acc; else knew[o - HDIM] = acc;
        }
    }
    if (h == 7) {   // v_new: one thread per output col; patch local row 63
        const float4* r4 = (const float4*)(wv + (size_t)tid * DD);
        float acc = 0.f;
        #pragma unroll 8
        for (int i = 0; i < 64; ++i) {
            const float4 t = r4[i];
            acc += t.x * hs[4 * i] + t.y * hs[4 * i + 1] + t.z * hs[4 * i + 2] + t.w * hs[4 * i + 3];
        }
        vs[63][tid] = acc + bvv;
    }
    __syncthreads();                                 // B3

    // ============ rope q (table row 1), fold 1/sqrt(HD) ============
    if (tid < HDIM) {
        const float te = qraw[tid & ~1], to = qraw[tid | 1];
        const float v = (tid & 1) ? (te * sq + to * cq) : (te * cq - to * sq);
        qr[tid] = v * 0.17677669529663687f;
    }
    __syncthreads();                                 // B4

    // ============ scores (pure reg/LDS) ============
    float svA, svB;
    {
        float acc = 0.f;
        #pragma unroll
        for (int i = 0; i < 8; ++i) {
            const float4 k = kA[i], c = cA[i], s = sA[i];
            const float k0 = k.x * c.x - k.y * s.x;
            const float k1 = k.x * s.x + k.y * c.x;
            const float k2 = k.z * c.z - k.w * s.z;
            const float k3 = k.z * s.z + k.w * c.z;
            acc += qr[4 * i] * k0 + qr[4 * i + 1] * k1 + qr[4 * i + 2] * k2 + qr[4 * i + 3] * k3;
        }
        svA = (mA == 0.0f) ? -INFINITY : acc;
    }
    {
        float acc = 0.f;
        if (w2 < NC) {
            #pragma unroll
            for (int i = 0; i < 8; ++i) {
                const float4 k = kB[i], c = cB[i], s = sB[i];
                const float k0 = k.x * c.x - k.y * s.x;
                const float k1 = k.x * s.x + k.y * c.x;
                const float k2 = k.z * c.z - k.w * s.z;
                const float k3 = k.z * s.z + k.w * c.z;
                acc += qr[4 * i] * k0 + qr[4 * i + 1] * k1 + qr[4 * i + 2] * k2 + qr[4 * i + 3] * k3;
            }
        } else {  // w == 511: k_new (roped with row 511 tables)
            #pragma unroll
            for (int i = 0; i < 8; ++i) {
                const float4 c = cB[i], s = sB[i];
                const float e0 = knew[4 * i], o0 = knew[4 * i + 1];
                const float e1 = knew[4 * i + 2], o1 = knew[4 * i + 3];
                const float k0 = e0 * c.x - o0 * s.x;
                const float k1 = e0 * s.x + o0 * c.x;
                const float k2 = e1 * c.z - o1 * s.z;
                const float k3 = e1 * s.z + o1 * c.z;
                acc += qr[4 * i] * k0 + qr[4 * i + 1] * k1 + qr[4 * i + 2] * k2 + qr[4 * i + 3] * k3;
            }
        }
        svB = (mB == 0.0f) ? -INFINITY : acc;
    }

    // ============ softmax over 512 ============
    float smax = fmaxf(svA, svB);
    #pragma unroll
    for (int off = 32; off > 0; off >>= 1) smax = fmaxf(smax, __shfl_down(smax, off, 64));
    if (lane == 0) red[wid] = smax;
    __syncthreads();                                 // B5
    const float gmax = fmaxf(fmaxf(red[0], red[1]), fmaxf(red[2], red[3]));
    const float eA = expf(svA - gmax);
    const float eB = expf(svB - gmax);
    probs[tid] = eA;
    probs[tid + 256] = eB;
    float esum = eA + eB;
    #pragma unroll
    for (int off = 32; off > 0; off >>= 1) esum += __shfl_down(esum, off, 64);
    __syncthreads();                                 // B6 (gmax reads done)
    if (lane == 0) red[wid] = esum;
    __syncthreads();                                 // B7
    const float inv = 1.0f / (red[0] + red[1] + red[2] + red[3]);

    // ============ PV: pure LDS ============
    const int hd  = tid & 31;
    const int seg = tid >> 5;                        // 0..7, 64 w's each
    float acc = 0.f;
    #pragma unroll 8
    for (int j = 0; j < 64; ++j) {
        const int w = seg * 64 + j;
        acc += probs[w] * vs[w >> 3][((w & 7) << 5) + hd];
    }
    pv[seg][hd] = acc;
    __syncthreads();                                 // B8

    // ============ reduce segments, residual, store ============
    if (tid < HDIM) {
        float oacc = 0.f;
        #pragma unroll
        for (int s2 = 0; s2 < 8; ++s2) oacc += pv[s2][tid];
        oacc = oacc * inv + xs[h * HDIM + tid];
        out[(size_t)b * DD + h * HDIM + tid] = oacc;
    }
}

extern "C" void kernel_launch(void* const* d_in, const int* in_sizes, int n_in,
                              void* d_out, int out_size, void* d_ws, size_t ws_size,
                              hipStream_t stream) {
    const float* emb     = (const float*)d_in[0];
    const int*   tokens  = (const int*)d_in[1];
    const float* pos_emb = (const float*)d_in[2];
    const float* rms_w   = (const float*)d_in[3];
    const float* wq      = (const float*)d_in[4];
    const float* bq      = (const float*)d_in[5];
    const float* wk      = (const float*)d_in[6];
    const float* bk      = (const float*)d_in[7];
    const float* wv      = (const float*)d_in[8];
    const float* bv      = (const float*)d_in[9];
    const float* kc      = (const float*)d_in[10];
    const float* vc      = (const float*)d_in[11];
    const float* cosd    = (const float*)d_in[12];
    const float* sind    = (const float*)d_in[13];
    const float* maskd   = (const float*)d_in[14];
    float* out           = (float*)d_out;

    fused_decode<<<dim3(BB * HH), dim3(256), 0, stream>>>(
        emb, tokens, pos_emb, rms_w, wq, bq, wk, bk, wv, bv,
        kc, vc, cosd, sind, maskd, out);
}